// Round 11
// baseline (919.073 us; speedup 1.0000x reference)
//
#include <hip/hip_runtime.h>
#include <hip/hip_bf16.h>
#include <cstdint>
#include <cstddef>

typedef __attribute__((ext_vector_type(8))) short bf16x8;
typedef __attribute__((ext_vector_type(4))) float f32x4;
typedef __attribute__((ext_vector_type(16))) float f32x16;
typedef __attribute__((ext_vector_type(4))) int i32x4;
typedef __attribute__((ext_vector_type(8))) int i32x8;
typedef __attribute__((ext_vector_type(4))) uint16_t u16x4;

#define GLOBAL_AS __attribute__((address_space(1)))
#define LDS_AS __attribute__((address_space(3)))

__device__ inline uint16_t f2b(float f) {
    uint32_t x = __float_as_uint(f);
    uint32_t r = (x + 0x7fffu + ((x >> 16) & 1u)) >> 16;
    return (uint16_t)r;
}

// ---------------------------------------------------------------- convert fp32 -> fragment-tiled fp8 (x64 prescale)
// Granule g (16 B) = ((m32*NT + kt)*128 + h*64 + lane)*16 bytes of output,
// holding fp8 of x[m32*32 + (lane&31)][kt*64 + (lane>>5)*32 + h*16 .. +16).
// This is exactly MFMA-lane `lane`'s reg-half h for fragment (m32, kt).
__global__ void cvt8t_kernel(const float* __restrict__ in, uint4* __restrict__ out,
                             int H, int NT, size_t n16) {
    size_t stride = (size_t)gridDim.x * blockDim.x;
    for (size_t g = (size_t)blockIdx.x * blockDim.x + threadIdx.x; g < n16; g += stride) {
        int lane = (int)(g & 63);
        int h = (int)((g >> 6) & 1);
        size_t rest = g >> 7;
        int kt = (int)(rest % (size_t)NT);
        size_t m32 = rest / (size_t)NT;
        int row = (int)(m32 * 32 + (lane & 31));
        int kb = kt * 64 + (lane >> 5) * 32 + h * 16;
        const float4* src = (const float4*)(in + (size_t)row * H + kb);
        float4 v0 = src[0], v1 = src[1], v2 = src[2], v3 = src[3];
        int w0 = __builtin_amdgcn_cvt_pk_fp8_f32(v0.x * 64.f, v0.y * 64.f, 0, false);
        w0 = __builtin_amdgcn_cvt_pk_fp8_f32(v0.z * 64.f, v0.w * 64.f, w0, true);
        int w1 = __builtin_amdgcn_cvt_pk_fp8_f32(v1.x * 64.f, v1.y * 64.f, 0, false);
        w1 = __builtin_amdgcn_cvt_pk_fp8_f32(v1.z * 64.f, v1.w * 64.f, w1, true);
        int w2 = __builtin_amdgcn_cvt_pk_fp8_f32(v2.x * 64.f, v2.y * 64.f, 0, false);
        w2 = __builtin_amdgcn_cvt_pk_fp8_f32(v2.z * 64.f, v2.w * 64.f, w2, true);
        int w3 = __builtin_amdgcn_cvt_pk_fp8_f32(v3.x * 64.f, v3.y * 64.f, 0, false);
        w3 = __builtin_amdgcn_cvt_pk_fp8_f32(v3.z * 64.f, v3.w * 64.f, w3, true);
        out[g] = make_uint4((unsigned)w0, (unsigned)w1, (unsigned)w2, (unsigned)w3);
    }
}

// ---------------------------------------------------------------- fp8 MX GEMM + fused LSE partials
// R11: NO LDS, NO barriers in the main loop. Fragments loaded directly from
// the fragment-tiled global layout: each load = 64 lanes x 16 B contiguous
// (1 KB/instr, perfectly coalesced). 256-thr blocks, 4 waves (2M x 2N),
// per-wave 64x64 (acc=64 AGPR). launch_bounds(256,3) -> 12 waves/CU, all
// free-running (pure TLP latency hiding; no lockstep, no barrier drains).
// L2 reuse via chunked XCD swizzle (same-W-panel blocks on one XCD).
// Epilogue: R8-style conflict-free LDS transpose, M=0 partials.

#define SC8 0x7F7F7F7F

#define MFMA8(aa, bb, cc) cc = __builtin_amdgcn_mfma_scale_f32_32x32x64_f8f6f4( \
        aa, bb, cc, 0, 0, 0, SC8, 0, SC8)

__device__ __forceinline__ i32x8 fragld(const uint8_t* p) {
    i32x4 lo = *(const i32x4*)p;
    i32x4 hi = *(const i32x4*)(p + 1024);
    i32x8 f;
    f[0] = lo[0]; f[1] = lo[1]; f[2] = lo[2]; f[3] = lo[3];
    f[4] = hi[0]; f[5] = hi[1]; f[6] = hi[2]; f[7] = hi[3];
    return f;
}

__global__ __launch_bounds__(256, 3)
void flce_gemm_fp8(const uint8_t* __restrict__ X8t, const uint8_t* __restrict__ W8t,
                   const long long* __restrict__ target,
                   float2* __restrict__ partials, float* __restrict__ tgt_logit,
                   int BT, int H, int V, int nrb) {
    __shared__ float redbuf[64 * 68];
    __shared__ int tgt_l[128];

    const int tid = threadIdx.x;
    const int lane = tid & 63, wave = tid >> 6;
    const int wr = wave >> 1, wc = wave & 1;     // 2(M) x 2(N)
    const int l31 = lane & 31;
    const int kq = lane >> 5;
    const int NT = H / 64;

    // bijective XCD swizzle (m204): nwg=8000 (%8==0) -> chunked, contiguous
    // wgid per XCD; rb-fastest so same-cb (W-panel) blocks share an XCD's L2.
    const int nwg = gridDim.x;
    const int q = nwg >> 3, rres = nwg & 7;
    const int xcd = blockIdx.x & 7, idx = blockIdx.x >> 3;
    const int wgid = (xcd < rres ? xcd * (q + 1) : rres * (q + 1) + (xcd - rres) * q) + idx;
    const int rb = wgid % nrb, cb = wgid / nrb;
    const int brow = rb * 128, bcol = cb * 128;

    // fragment base pointers (m32 = 32-row block index in the tiled layout)
    const int mA0 = (brow >> 5) + wr * 2;
    const int nB0 = (bcol >> 5) + wc * 2;
    const uint8_t* pA0 = X8t + (size_t)mA0 * NT * 2048 + lane * 16;
    const uint8_t* pA1 = X8t + (size_t)(mA0 + 1) * NT * 2048 + lane * 16;
    const uint8_t* pB0 = W8t + (size_t)nB0 * NT * 2048 + lane * 16;
    const uint8_t* pB1 = W8t + (size_t)(nB0 + 1) * NT * 2048 + lane * 16;

    f32x16 acc00 = {}, acc01 = {}, acc10 = {}, acc11 = {};

#pragma unroll 2
    for (int kt = 0; kt < NT; ++kt) {
        const size_t o = (size_t)kt * 2048;
        i32x8 a0 = fragld(pA0 + o);
        i32x8 a1 = fragld(pA1 + o);
        i32x8 b0 = fragld(pB0 + o);
        i32x8 b1 = fragld(pB1 + o);
        __builtin_amdgcn_s_setprio(1);
        MFMA8(a0, b0, acc00);
        MFMA8(a0, b1, acc01);
        MFMA8(a1, b0, acc10);
        MFMA8(a1, b1, acc11);
        __builtin_amdgcn_s_setprio(0);
    }

    // ---- epilogue: conflict-free LDS transpose, M=0 partials
    if (tid < 128) {
        long long tt = target[brow + tid];
        if (tt < 0) tt = 0;
        if (tt >= V) tt = (long long)V - 1;
        tgt_l[tid] = (int)tt;
    }
    __syncthreads();

    const float inv = 1.0f / 4096.0f;
    const int c0 = wc * 64 + l31;
#pragma unroll
    for (int p = 0; p < 2; ++p) {
        if (wr == p) {                             // writers: 2 waves (wc = 0,1)
#pragma unroll
            for (int mi = 0; mi < 2; ++mi) {
                const f32x16* a0 = mi ? &acc10 : &acc00;
                const f32x16* a1 = mi ? &acc11 : &acc01;
#pragma unroll
                for (int j = 0; j < 16; ++j) {
                    int rif = (j & 3) + 8 * (j >> 2) + 4 * kq;
                    int rl = mi * 32 + rif;
                    int grow = p * 64 + rl;
                    int tc = tgt_l[grow] - bcol;
                    float v0 = (*a0)[j] * inv;
                    float v1 = (*a1)[j] * inv;
                    if (tc == c0) tgt_logit[brow + grow] = v0;
                    if (tc == c0 + 32) tgt_logit[brow + grow] = v1;
                    redbuf[rl * 68 + wc * 32 + l31] = __expf(v0) + __expf(v1);
                }
            }
        }
        __syncthreads();
        if (wave == p) {                           // reader: 1 wave sums 64 x 64
            const f32x4* rp = (const f32x4*)(redbuf + lane * 68);
            f32x4 s4 = {0.f, 0.f, 0.f, 0.f};
#pragma unroll
            for (int c = 0; c < 16; ++c) {
                f32x4 v = rp[c];
                s4[0] += v[0]; s4[1] += v[1]; s4[2] += v[2]; s4[3] += v[3];
            }
            float S = (s4[0] + s4[1]) + (s4[2] + s4[3]);
            partials[(size_t)cb * BT + brow + p * 64 + lane] = make_float2(0.f, S);
        }
        __syncthreads();
    }
}

// ---------------------------------------------------------------- fp32 fallback (128^2, m97 structure)
__global__ void flce_gemm_f32(const float* __restrict__ X, const float* __restrict__ Wf,
                              const long long* __restrict__ target,
                              float2* __restrict__ partials, float* __restrict__ tgt_logit,
                              int BT, int H, int V, int nrb) {
    __shared__ uint16_t As[128 * 32];
    __shared__ uint16_t Bs[128 * 32];
    __shared__ float red_m[128][2];
    __shared__ float red_s[128][2];
    __shared__ int tgt_l[128];

    const int tid = threadIdx.x;
    const int wave = tid >> 6, lane = tid & 63;
    const int wr = wave >> 1, wc = wave & 1;
    const int l16 = lane & 15, lh = lane >> 4;
    const int bid = blockIdx.x;
    const int rb = bid % nrb, cb = bid / nrb;
    const int brow = rb * 128, bcol = cb * 128;

    if (tid < 128) {
        long long t = target[brow + tid];
        if (t < 0) t = 0;
        if (t >= V) t = (long long)V - 1;
        tgt_l[tid] = (int)t;
    }

    f32x4 acc[4][4] = {};
    for (int k0 = 0; k0 < H; k0 += 32) {
        __syncthreads();
#pragma unroll
        for (int j = 0; j < 4; ++j) {
            int fi = tid + j * 256;
            int row = fi >> 3;
            int kk = (fi & 7) << 2;
            float4 av = *(const float4*)(X + (size_t)(brow + row) * H + k0 + kk);
            float4 bv = *(const float4*)(Wf + (size_t)(bcol + row) * H + k0 + kk);
            u16x4 au, bu;
            au[0] = f2b(av.x); au[1] = f2b(av.y); au[2] = f2b(av.z); au[3] = f2b(av.w);
            bu[0] = f2b(bv.x); bu[1] = f2b(bv.y); bu[2] = f2b(bv.z); bu[3] = f2b(bv.w);
            *(u16x4*)&As[row * 32 + kk] = au;
            *(u16x4*)&Bs[row * 32 + kk] = bu;
        }
        __syncthreads();
        bf16x8 af[4], bf[4];
#pragma unroll
        for (int m = 0; m < 4; ++m)
            af[m] = *(const bf16x8*)&As[(wr * 64 + m * 16 + l16) * 32 + lh * 8];
#pragma unroll
        for (int n = 0; n < 4; ++n)
            bf[n] = *(const bf16x8*)&Bs[(wc * 64 + n * 16 + l16) * 32 + lh * 8];
#pragma unroll
        for (int m = 0; m < 4; ++m)
#pragma unroll
            for (int n = 0; n < 4; ++n)
                acc[m][n] = __builtin_amdgcn_mfma_f32_16x16x32_bf16(af[m], bf[n], acc[m][n], 0, 0, 0);
    }
#pragma unroll
    for (int m = 0; m < 4; ++m) {
#pragma unroll
        for (int r = 0; r < 4; ++r) {
            int rowl = wr * 64 + m * 16 + lh * 4 + r;
            int tc = tgt_l[rowl] - bcol;
            float mx = -INFINITY;
#pragma unroll
            for (int n = 0; n < 4; ++n) {
                float v = acc[m][n][r];
                if (tc == wc * 64 + n * 16 + l16) tgt_logit[brow + rowl] = v;
                mx = fmaxf(mx, v);
            }
#pragma unroll
            for (int d = 1; d < 16; d <<= 1) mx = fmaxf(mx, __shfl_xor(mx, d));
            float s = 0.f;
#pragma unroll
            for (int n = 0; n < 4; ++n) s += __expf(acc[m][n][r] - mx);
#pragma unroll
            for (int d = 1; d < 16; d <<= 1) s += __shfl_xor(s, d);
            if (l16 == 0) { red_m[rowl][wc] = mx; red_s[rowl][wc] = s; }
        }
    }
    __syncthreads();
    if (tid < 128) {
        float m0 = red_m[tid][0], m1 = red_m[tid][1];
        float s0 = red_s[tid][0], s1 = red_s[tid][1];
        float M = fmaxf(m0, m1);
        float S = s0 * __expf(m0 - M) + s1 * __expf(m1 - M);
        partials[(size_t)cb * BT + brow + tid] = make_float2(M, S);
    }
}

// ---------------------------------------------------------------- per-row LSE merge + block sums
__global__ void flce_reduce(const float2* __restrict__ partials,
                            const float* __restrict__ tgt_logit,
                            const long long* __restrict__ target,
                            float2* __restrict__ bsums, int BT, int NCB) {
    int row = blockIdx.x * blockDim.x + threadIdx.x;
    float M = -INFINITY, S = 0.f;
    for (int cbi = 0; cbi < NCB; ++cbi) {
        float2 p = partials[(size_t)cbi * BT + row];
        float Mn = fmaxf(M, p.x);
        S = S * __expf(M - Mn) + p.y * __expf(p.x - Mn);
        M = Mn;
    }
    float lse = M + __logf(S);
    bool valid = (target[row] != -100);
    float nll = valid ? (lse - tgt_logit[row]) : 0.f;
    float cnt = valid ? 1.f : 0.f;
#pragma unroll
    for (int d = 1; d < 64; d <<= 1) { nll += __shfl_xor(nll, d); cnt += __shfl_xor(cnt, d); }
    __shared__ float sm[8][2];
    int w = threadIdx.x >> 6;
    if ((threadIdx.x & 63) == 0) { sm[w][0] = nll; sm[w][1] = cnt; }
    __syncthreads();
    if (threadIdx.x == 0) {
        float sn = 0.f, sc = 0.f;
        int nw = blockDim.x >> 6;
        for (int i = 0; i < nw; ++i) { sn += sm[i][0]; sc += sm[i][1]; }
        bsums[blockIdx.x] = make_float2(sn, sc);
    }
}

__global__ void flce_final(const float2* __restrict__ bsums, int nb, float* __restrict__ out) {
    if (blockIdx.x == 0 && threadIdx.x == 0) {
        float sn = 0.f, sc = 0.f;
        for (int i = 0; i < nb; ++i) { sn += bsums[i].x; sc += bsums[i].y; }
        out[0] = sn / sc;
    }
}

// ---------------------------------------------------------------- launch
extern "C" void kernel_launch(void* const* d_in, const int* in_sizes, int n_in,
                              void* d_out, int out_size, void* d_ws, size_t ws_size,
                              hipStream_t stream) {
    const float* x = (const float*)d_in[0];
    const float* w = (const float*)d_in[1];
    const long long* target = (const long long*)d_in[2];
    float* out = (float*)d_out;

    const int BT = in_sizes[2];
    const int H = in_sizes[0] / BT;
    const int V = in_sizes[1] / H;
    const int NT = H / 64;
    const int nred = BT / 256;

    char* ws = (char*)d_ws;
    size_t szW = (size_t)V * H;            // fp8: 1 B/elem
    size_t szX = (size_t)BT * H;
    const int nrb = BT / 128;              // 32
    const int ncb = V / 128;               // 250
    size_t szPart = (size_t)ncb * BT * sizeof(float2);
    size_t szTgt = (size_t)BT * sizeof(float);
    size_t szB = (size_t)nred * sizeof(float2);

    bool use8 = ws_size >= szW + szX + szPart + szTgt + szB;

    if (use8) {
        uint8_t* W8t = (uint8_t*)ws;
        uint8_t* X8t = (uint8_t*)(ws + szW);
        float2* partials = (float2*)(ws + szW + szX);
        float* tgtlog = (float*)(ws + szW + szX + szPart);
        float2* bsums = (float2*)(ws + szW + szX + szPart + szTgt);

        hipLaunchKernelGGL(cvt8t_kernel, dim3(1024), dim3(256), 0, stream,
                           x, (uint4*)X8t, H, NT, (size_t)BT * H / 16);
        hipLaunchKernelGGL(cvt8t_kernel, dim3(4096), dim3(256), 0, stream,
                           w, (uint4*)W8t, H, NT, (size_t)V * H / 16);
        hipLaunchKernelGGL(flce_gemm_fp8, dim3(nrb * ncb), dim3(256), 0, stream,
                           X8t, W8t, target, partials, tgtlog, BT, H, V, nrb);
        hipLaunchKernelGGL(flce_reduce, dim3(BT / 256), dim3(256), 0, stream,
                           partials, tgtlog, target, bsums, BT, ncb);
        hipLaunchKernelGGL(flce_final, dim3(1), dim3(64), 0, stream, bsums, nred, out);
    } else {
        const int nrb1 = BT / 128, ncb1 = V / 128;
        float2* partials = (float2*)ws;
        float* tgtlog = (float*)(ws + (size_t)ncb1 * BT * sizeof(float2));
        float2* bsums = (float2*)(ws + (size_t)ncb1 * BT * sizeof(float2) + szTgt);
        hipLaunchKernelGGL(flce_gemm_f32, dim3(nrb1 * ncb1), dim3(256), 0, stream,
                           x, w, target, partials, tgtlog, BT, H, V, nrb1);
        hipLaunchKernelGGL(flce_reduce, dim3(BT / 256), dim3(256), 0, stream,
                           partials, tgtlog, target, bsums, BT, ncb1);
        hipLaunchKernelGGL(flce_final, dim3(1), dim3(64), 0, stream, bsums, nred, out);
    }
}

// Round 12
// 673.977 us; speedup vs baseline: 1.3637x; 1.3637x over previous
//
#include <hip/hip_runtime.h>
#include <hip/hip_bf16.h>
#include <cstdint>
#include <cstddef>

typedef __attribute__((ext_vector_type(8))) short bf16x8;
typedef __attribute__((ext_vector_type(4))) float f32x4;
typedef __attribute__((ext_vector_type(16))) float f32x16;
typedef __attribute__((ext_vector_type(4))) int i32x4;
typedef __attribute__((ext_vector_type(8))) int i32x8;
typedef __attribute__((ext_vector_type(4))) uint16_t u16x4;

#define GLOBAL_AS __attribute__((address_space(1)))
#define LDS_AS __attribute__((address_space(3)))

__device__ inline uint16_t f2b(float f) {
    uint32_t x = __float_as_uint(f);
    uint32_t r = (x + 0x7fffu + ((x >> 16) & 1u)) >> 16;
    return (uint16_t)r;
}

// ---------------------------------------------------------------- convert fp32 -> fragment-tiled fp8 (x64 prescale)
// Granule g (16 B) = ((m32*NT + kt)*128 + h*64 + lane)*16 bytes of output,
// holding fp8 of x[m32*32 + (lane&31)][kt*64 + (lane>>5)*32 + h*16 .. +16).
// Verified end-to-end in R11.
__global__ void cvt8t_kernel(const float* __restrict__ in, uint4* __restrict__ out,
                             int H, int NT, size_t n16) {
    size_t stride = (size_t)gridDim.x * blockDim.x;
    for (size_t g = (size_t)blockIdx.x * blockDim.x + threadIdx.x; g < n16; g += stride) {
        int lane = (int)(g & 63);
        int h = (int)((g >> 6) & 1);
        size_t rest = g >> 7;
        int kt = (int)(rest % (size_t)NT);
        size_t m32 = rest / (size_t)NT;
        int row = (int)(m32 * 32 + (lane & 31));
        int kb = kt * 64 + (lane >> 5) * 32 + h * 16;
        const float4* src = (const float4*)(in + (size_t)row * H + kb);
        float4 v0 = src[0], v1 = src[1], v2 = src[2], v3 = src[3];
        int w0 = __builtin_amdgcn_cvt_pk_fp8_f32(v0.x * 64.f, v0.y * 64.f, 0, false);
        w0 = __builtin_amdgcn_cvt_pk_fp8_f32(v0.z * 64.f, v0.w * 64.f, w0, true);
        int w1 = __builtin_amdgcn_cvt_pk_fp8_f32(v1.x * 64.f, v1.y * 64.f, 0, false);
        w1 = __builtin_amdgcn_cvt_pk_fp8_f32(v1.z * 64.f, v1.w * 64.f, w1, true);
        int w2 = __builtin_amdgcn_cvt_pk_fp8_f32(v2.x * 64.f, v2.y * 64.f, 0, false);
        w2 = __builtin_amdgcn_cvt_pk_fp8_f32(v2.z * 64.f, v2.w * 64.f, w2, true);
        int w3 = __builtin_amdgcn_cvt_pk_fp8_f32(v3.x * 64.f, v3.y * 64.f, 0, false);
        w3 = __builtin_amdgcn_cvt_pk_fp8_f32(v3.z * 64.f, v3.w * 64.f, w3, true);
        out[g] = make_uint4((unsigned)w0, (unsigned)w1, (unsigned)w2, (unsigned)w3);
    }
}

// ---------------------------------------------------------------- fp8 MX GEMM + fused LSE partials
// R12 = R8's schedule (proven 576 us) + R11's fragment-tiled layout (proven
// 0-conflict): LDS holds whole fragments; staging src = 1 KB contiguous/instr,
// LDS dest linear, frag reads = ds_read_b128 at base+lane*16 (sequential ->
// conflict-free BY CONSTRUCTION, no swizzle). Tile 256x128, 8 waves 4Mx2N,
// per-wave 64x64 (acc=64 AGPR), BK=64, 3 buffers x 24 KB, stage t+2 at top,
// vmcnt(3) drains t+1, one barrier/tile, launch_bounds(512,4) -> 2 blocks/CU.

#define SC8 0x7F7F7F7F

#define MFMA8(aa, bb, cc) cc = __builtin_amdgcn_mfma_scale_f32_32x32x64_f8f6f4( \
        aa, bb, cc, 0, 0, 0, SC8, 0, SC8)

__global__ __launch_bounds__(512, 4)
void flce_gemm_fp8(const uint8_t* __restrict__ X8t, const uint8_t* __restrict__ W8t,
                   const long long* __restrict__ target,
                   float2* __restrict__ partials, float* __restrict__ tgt_logit,
                   int BT, int H, int V, int nrb) {
    __shared__ __align__(16) char smem[73728];   // 3 buffers x 24 KB (A 16K + B 8K)
#define BUF(i) (smem + (i) * 24576)

    const int tid = threadIdx.x;
    const int lane = tid & 63, wave = tid >> 6;
    const int wr = wave >> 1, wc = wave & 1;     // 4(M) x 2(N)
    const int l31 = lane & 31;
    const int kq = lane >> 5;
    const int NT = H / 64;

    // bijective XCD swizzle (m204), rb-fastest (nwg=4000, %8==0)
    const int nwg = gridDim.x;
    const int q = nwg >> 3, rres = nwg & 7;
    const int xcd = blockIdx.x & 7, idx = blockIdx.x >> 3;
    const int wgid = (xcd < rres ? xcd * (q + 1) : rres * (q + 1) + (xcd - rres) * q) + idx;
    const int rb = wgid % nrb, cb = wgid / nrb;
    const int brow = rb * 256, bcol = cb * 128;

    // per-wave staging granules: g = 3*wave + j.  Granule g (1 KB):
    //   g < 16: A frag fi=g>>1 (m32 = rb*8+fi), half h=g&1
    //   g >=16: B frag fj=(g-16)>>1 (n32 = cb*4+fj), half h=(g-16)&1
    // dst is uniformly g*1024 + lane*16 (A at 0..16K, B at 16K..24K).
    const int g0 = 3 * wave, g1 = g0 + 1, g2 = g0 + 2;
#define GSRC(g) ((g) < 16 \
        ? X8t + ((size_t)(rb * 8 + ((g) >> 1)) * NT) * 2048 + ((g) & 1) * 1024 + lane * 16 \
        : W8t + ((size_t)(cb * 4 + (((g) - 16) >> 1)) * NT) * 2048 + (((g) - 16) & 1) * 1024 + lane * 16)
    const uint8_t* s0 = GSRC(g0);
    const uint8_t* s1 = GSRC(g1);
    const uint8_t* s2 = GSRC(g2);
    const int d0 = g0 * 1024 + lane * 16;
    const int d1 = d0 + 1024;
    const int d2 = d0 + 2048;
#undef GSRC

#define STG(gp, lp) __builtin_amdgcn_global_load_lds( \
        (const GLOBAL_AS uint32_t*)(gp), (LDS_AS uint32_t*)(lp), 16, 0, 0)
#define STAGE_TILE(buf, kt_) do { \
        const size_t o_ = (size_t)(kt_) * 2048; \
        STG(s0 + o_, (buf) + d0); \
        STG(s1 + o_, (buf) + d1); \
        STG(s2 + o_, (buf) + d2); \
    } while (0)

    // fragment read bases (linear: base + lane*16 / +1024)
    const int aO0 = (2 * wr) * 2048 + lane * 16;
    const int aO1 = aO0 + 2048;
    const int bO0 = 16384 + (2 * wc) * 2048 + lane * 16;
    const int bO1 = bO0 + 2048;

#define FRAGLD(dst, buf, off) do { \
        i32x4 lo_ = *(const i32x4*)((buf) + (off)); \
        i32x4 hi_ = *(const i32x4*)((buf) + (off) + 1024); \
        dst[0] = lo_[0]; dst[1] = lo_[1]; dst[2] = lo_[2]; dst[3] = lo_[3]; \
        dst[4] = hi_[0]; dst[5] = hi_[1]; dst[6] = hi_[2]; dst[7] = hi_[3]; \
    } while (0)

    f32x16 acc00 = {}, acc01 = {}, acc10 = {}, acc11 = {};

    char *Bc = BUF(0), *Bn = BUF(1), *Bf = BUF(2);

    // ---- prologue: stage T0, T1; drain T0; barrier
    STAGE_TILE(Bc, 0);
    if (NT > 1) {
        STAGE_TILE(Bn, 1);
        asm volatile("s_waitcnt vmcnt(3)" ::: "memory");
    } else {
        asm volatile("s_waitcnt vmcnt(0)" ::: "memory");
    }
    __builtin_amdgcn_s_barrier();

    for (int t = 0; t < NT; ++t) {
        if (t + 2 < NT) STAGE_TILE(Bf, t + 2);

        i32x8 a0, a1, b0, b1;
        FRAGLD(a0, Bc, aO0);
        FRAGLD(a1, Bc, aO1);
        FRAGLD(b0, Bc, bO0);
        FRAGLD(b1, Bc, bO1);

        __builtin_amdgcn_s_setprio(1);
        MFMA8(a0, b0, acc00);
        MFMA8(a0, b1, acc01);
        MFMA8(a1, b0, acc10);
        MFMA8(a1, b1, acc11);
        __builtin_amdgcn_s_setprio(0);

        if (t + 2 < NT)      asm volatile("s_waitcnt vmcnt(3)" ::: "memory");
        else if (t + 1 < NT) asm volatile("s_waitcnt vmcnt(0)" ::: "memory");
        __builtin_amdgcn_s_barrier();

        char* tb = Bc; Bc = Bn; Bn = Bf; Bf = tb;
    }

    // ---- epilogue: conflict-free LDS partial-sum transpose, M=0 partials (R8)
    __syncthreads();
    int* tgt_l = (int*)(smem + 33280);
    if (tid < 256) {
        long long tt = target[brow + tid];
        if (tt < 0) tt = 0;
        if (tt >= V) tt = (long long)V - 1;
        tgt_l[tid] = (int)tt;
    }
    __syncthreads();

    const float inv = 1.0f / 4096.0f;
    const int c0 = wc * 64 + l31;
#pragma unroll
    for (int p = 0; p < 2; ++p) {
        if ((wr >> 1) == p) {                      // writers: waves with wr in {2p, 2p+1}
            float* reg = (float*)(smem + (wr & 1) * 16640);   // [64][65]
#pragma unroll
            for (int mi = 0; mi < 2; ++mi) {
                const f32x16* a0 = mi ? &acc10 : &acc00;
                const f32x16* a1 = mi ? &acc11 : &acc01;
#pragma unroll
                for (int j = 0; j < 16; ++j) {
                    int rif = (j & 3) + 8 * (j >> 2) + 4 * kq;
                    int rl = mi * 32 + rif;
                    int grow = wr * 64 + rl;
                    int tc = tgt_l[grow] - bcol;
                    float v0 = (*a0)[j] * inv;
                    float v1 = (*a1)[j] * inv;
                    if (tc == c0) tgt_logit[brow + grow] = v0;
                    if (tc == c0 + 32) tgt_logit[brow + grow] = v1;
                    reg[rl * 65 + wc * 32 + l31] = __expf(v0) + __expf(v1);
                }
            }
        }
        __syncthreads();
        if ((wave >> 1) == p) {                    // readers: waves 2p, 2p+1
            const int rw = wave & 1;
            const float* reg = (const float*)(smem + rw * 16640);
            float S = 0.f;
#pragma unroll
            for (int c = 0; c < 64; ++c) S += reg[lane * 65 + c];
            int grow = (2 * p + rw) * 64 + lane;
            partials[(size_t)cb * BT + brow + grow] = make_float2(0.f, S);
        }
        __syncthreads();
    }
#undef BUF
#undef STG
#undef STAGE_TILE
#undef FRAGLD
}

// ---------------------------------------------------------------- fp32 fallback (128^2, m97 structure)
__global__ void flce_gemm_f32(const float* __restrict__ X, const float* __restrict__ Wf,
                              const long long* __restrict__ target,
                              float2* __restrict__ partials, float* __restrict__ tgt_logit,
                              int BT, int H, int V, int nrb) {
    __shared__ uint16_t As[128 * 32];
    __shared__ uint16_t Bs[128 * 32];
    __shared__ float red_m[128][2];
    __shared__ float red_s[128][2];
    __shared__ int tgt_l[128];

    const int tid = threadIdx.x;
    const int wave = tid >> 6, lane = tid & 63;
    const int wr = wave >> 1, wc = wave & 1;
    const int l16 = lane & 15, lh = lane >> 4;
    const int bid = blockIdx.x;
    const int rb = bid % nrb, cb = bid / nrb;
    const int brow = rb * 128, bcol = cb * 128;

    if (tid < 128) {
        long long t = target[brow + tid];
        if (t < 0) t = 0;
        if (t >= V) t = (long long)V - 1;
        tgt_l[tid] = (int)t;
    }

    f32x4 acc[4][4] = {};
    for (int k0 = 0; k0 < H; k0 += 32) {
        __syncthreads();
#pragma unroll
        for (int j = 0; j < 4; ++j) {
            int fi = tid + j * 256;
            int row = fi >> 3;
            int kk = (fi & 7) << 2;
            float4 av = *(const float4*)(X + (size_t)(brow + row) * H + k0 + kk);
            float4 bv = *(const float4*)(Wf + (size_t)(bcol + row) * H + k0 + kk);
            u16x4 au, bu;
            au[0] = f2b(av.x); au[1] = f2b(av.y); au[2] = f2b(av.z); au[3] = f2b(av.w);
            bu[0] = f2b(bv.x); bu[1] = f2b(bv.y); bu[2] = f2b(bv.z); bu[3] = f2b(bv.w);
            *(u16x4*)&As[row * 32 + kk] = au;
            *(u16x4*)&Bs[row * 32 + kk] = bu;
        }
        __syncthreads();
        bf16x8 af[4], bf[4];
#pragma unroll
        for (int m = 0; m < 4; ++m)
            af[m] = *(const bf16x8*)&As[(wr * 64 + m * 16 + l16) * 32 + lh * 8];
#pragma unroll
        for (int n = 0; n < 4; ++n)
            bf[n] = *(const bf16x8*)&Bs[(wc * 64 + n * 16 + l16) * 32 + lh * 8];
#pragma unroll
        for (int m = 0; m < 4; ++m)
#pragma unroll
            for (int n = 0; n < 4; ++n)
                acc[m][n] = __builtin_amdgcn_mfma_f32_16x16x32_bf16(af[m], bf[n], acc[m][n], 0, 0, 0);
    }
#pragma unroll
    for (int m = 0; m < 4; ++m) {
#pragma unroll
        for (int r = 0; r < 4; ++r) {
            int rowl = wr * 64 + m * 16 + lh * 4 + r;
            int tc = tgt_l[rowl] - bcol;
            float mx = -INFINITY;
#pragma unroll
            for (int n = 0; n < 4; ++n) {
                float v = acc[m][n][r];
                if (tc == wc * 64 + n * 16 + l16) tgt_logit[brow + rowl] = v;
                mx = fmaxf(mx, v);
            }
#pragma unroll
            for (int d = 1; d < 16; d <<= 1) mx = fmaxf(mx, __shfl_xor(mx, d));
            float s = 0.f;
#pragma unroll
            for (int n = 0; n < 4; ++n) s += __expf(acc[m][n][r] - mx);
#pragma unroll
            for (int d = 1; d < 16; d <<= 1) s += __shfl_xor(s, d);
            if (l16 == 0) { red_m[rowl][wc] = mx; red_s[rowl][wc] = s; }
        }
    }
    __syncthreads();
    if (tid < 128) {
        float m0 = red_m[tid][0], m1 = red_m[tid][1];
        float s0 = red_s[tid][0], s1 = red_s[tid][1];
        float M = fmaxf(m0, m1);
        float S = s0 * __expf(m0 - M) + s1 * __expf(m1 - M);
        partials[(size_t)cb * BT + brow + tid] = make_float2(M, S);
    }
}

// ---------------------------------------------------------------- per-row LSE merge + block sums
__global__ void flce_reduce(const float2* __restrict__ partials,
                            const float* __restrict__ tgt_logit,
                            const long long* __restrict__ target,
                            float2* __restrict__ bsums, int BT, int NCB) {
    int row = blockIdx.x * blockDim.x + threadIdx.x;
    float M = -INFINITY, S = 0.f;
    for (int cbi = 0; cbi < NCB; ++cbi) {
        float2 p = partials[(size_t)cbi * BT + row];
        float Mn = fmaxf(M, p.x);
        S = S * __expf(M - Mn) + p.y * __expf(p.x - Mn);
        M = Mn;
    }
    float lse = M + __logf(S);
    bool valid = (target[row] != -100);
    float nll = valid ? (lse - tgt_logit[row]) : 0.f;
    float cnt = valid ? 1.f : 0.f;
#pragma unroll
    for (int d = 1; d < 64; d <<= 1) { nll += __shfl_xor(nll, d); cnt += __shfl_xor(cnt, d); }
    __shared__ float sm[8][2];
    int w = threadIdx.x >> 6;
    if ((threadIdx.x & 63) == 0) { sm[w][0] = nll; sm[w][1] = cnt; }
    __syncthreads();
    if (threadIdx.x == 0) {
        float sn = 0.f, sc = 0.f;
        int nw = blockDim.x >> 6;
        for (int i = 0; i < nw; ++i) { sn += sm[i][0]; sc += sm[i][1]; }
        bsums[blockIdx.x] = make_float2(sn, sc);
    }
}

__global__ void flce_final(const float2* __restrict__ bsums, int nb, float* __restrict__ out) {
    if (blockIdx.x == 0 && threadIdx.x == 0) {
        float sn = 0.f, sc = 0.f;
        for (int i = 0; i < nb; ++i) { sn += bsums[i].x; sc += bsums[i].y; }
        out[0] = sn / sc;
    }
}

// ---------------------------------------------------------------- launch
extern "C" void kernel_launch(void* const* d_in, const int* in_sizes, int n_in,
                              void* d_out, int out_size, void* d_ws, size_t ws_size,
                              hipStream_t stream) {
    const float* x = (const float*)d_in[0];
    const float* w = (const float*)d_in[1];
    const long long* target = (const long long*)d_in[2];
    float* out = (float*)d_out;

    const int BT = in_sizes[2];
    const int H = in_sizes[0] / BT;
    const int V = in_sizes[1] / H;
    const int NT = H / 64;
    const int nred = BT / 256;

    char* ws = (char*)d_ws;
    size_t szW = (size_t)V * H;            // fp8: 1 B/elem
    size_t szX = (size_t)BT * H;
    const int nrb = BT / 256;              // 16
    const int ncb = V / 128;               // 250
    size_t szPart = (size_t)ncb * BT * sizeof(float2);
    size_t szTgt = (size_t)BT * sizeof(float);
    size_t szB = (size_t)nred * sizeof(float2);

    bool use8 = ws_size >= szW + szX + szPart + szTgt + szB;

    if (use8) {
        uint8_t* W8t = (uint8_t*)ws;
        uint8_t* X8t = (uint8_t*)(ws + szW);
        float2* partials = (float2*)(ws + szW + szX);
        float* tgtlog = (float*)(ws + szW + szX + szPart);
        float2* bsums = (float2*)(ws + szW + szX + szPart + szTgt);

        hipLaunchKernelGGL(cvt8t_kernel, dim3(1024), dim3(256), 0, stream,
                           x, (uint4*)X8t, H, NT, (size_t)BT * H / 16);
        hipLaunchKernelGGL(cvt8t_kernel, dim3(4096), dim3(256), 0, stream,
                           w, (uint4*)W8t, H, NT, (size_t)V * H / 16);
        hipLaunchKernelGGL(flce_gemm_fp8, dim3(nrb * ncb), dim3(512), 0, stream,
                           X8t, W8t, target, partials, tgtlog, BT, H, V, nrb);
        hipLaunchKernelGGL(flce_reduce, dim3(BT / 256), dim3(256), 0, stream,
                           partials, tgtlog, target, bsums, BT, ncb);
        hipLaunchKernelGGL(flce_final, dim3(1), dim3(64), 0, stream, bsums, nred, out);
    } else {
        const int nrb1 = BT / 128, ncb1 = V / 128;
        float2* partials = (float2*)ws;
        float* tgtlog = (float*)(ws + (size_t)ncb1 * BT * sizeof(float2));
        float2* bsums = (float2*)(ws + (size_t)ncb1 * BT * sizeof(float2) + szTgt);
        hipLaunchKernelGGL(flce_gemm_f32, dim3(nrb1 * ncb1), dim3(256), 0, stream,
                           x, w, target, partials, tgtlog, BT, H, V, nrb1);
        hipLaunchKernelGGL(flce_reduce, dim3(BT / 256), dim3(256), 0, stream,
                           partials, tgtlog, target, bsums, BT, ncb1);
        hipLaunchKernelGGL(flce_final, dim3(1), dim3(64), 0, stream, bsums, nred, out);
    }
}